// Round 6
// baseline (2880.611 us; speedup 1.0000x reference)
//
#include <hip/hip_runtime.h>
#include <cstdint>
#include <cstddef>

// Problem constants
#define kSEQ 100
#define kB   200
#define kNP  512
#define kNG  4096
#define kMP  256     // padded M for recurrent/encoder GEMMs
#define KSPLIT 8

typedef _Float16 f16_t;
typedef f16_t f16x8 __attribute__((ext_vector_type(8)));
typedef f16_t f16x4 __attribute__((ext_vector_type(4)));
typedef float f32x4 __attribute__((ext_vector_type(4)));

// ---------------------------------------------------------------------------
// Pack fp32 row-major [srcM x srcK] into MFMA fragment order fp16:
// dst[fid][lane][j] with fid = m16*KB + kb, value = src[m16*16 + (lane&15)]
//                                                      [kb*32 + (lane>>4)*8 + j]
// OOB rows (row >= srcM) are zero-filled.  4 fragments per 256-thread block.
// ---------------------------------------------------------------------------
__global__ __launch_bounds__(256)
void k_pack(const float* __restrict__ src, f16_t* __restrict__ dst,
            int KB, int srcM, int srcK, int nFrag) {
    const int fid = blockIdx.x * 4 + (threadIdx.x >> 6);
    if (fid >= nFrag) return;
    const int lane = threadIdx.x & 63;
    const int m16  = fid / KB;
    const int kb   = fid - m16 * KB;
    const int row  = m16 * 16 + (lane & 15);
    const int kcol = kb * 32 + (lane >> 4) * 8;
    f16x8 h = {};
    if (row < srcM) {
        const float4* s = (const float4*)(src + (size_t)row * srcK + kcol);
        float4 v0 = s[0], v1 = s[1];
        h[0] = (f16_t)v0.x; h[1] = (f16_t)v0.y; h[2] = (f16_t)v0.z; h[3] = (f16_t)v0.w;
        h[4] = (f16_t)v1.x; h[5] = (f16_t)v1.y; h[6] = (f16_t)v1.z; h[7] = (f16_t)v1.w;
    }
    *(f16x8*)(dst + (size_t)fid * 512 + (size_t)lane * 8) = h;
}

// ---------------------------------------------------------------------------
// LDS-free fp16 MFMA GEMM on fragment-packed operands.
// part[ks][m][n] = sum_k A[m][k]*B[n][k] over this block's K-chunk.
// A_pk: [kMP/16][KB] fragments; B_pk: [4096/16][KB] fragments.
// Grid: (32 n-tiles, 2 m-tiles, KSPLIT), 256 thr = 4 waves of 64x64.
// No LDS, no barriers: every fragment load is a coalesced 1KB burst.
// ---------------------------------------------------------------------------
__global__ __launch_bounds__(256)
void k_gemm_pk(const f16_t* __restrict__ A, const f16_t* __restrict__ B,
               int KB, float* __restrict__ part) {
    const int tid  = threadIdx.x;
    const int lane = tid & 63;
    const int wid  = tid >> 6;
    const int wr   = wid >> 1;
    const int wc   = wid & 1;
    const int m0   = blockIdx.y * 128;
    const int n0   = blockIdx.x * 128;
    const int nkb  = KB / KSPLIT;
    const int kb0  = blockIdx.z * nkb;

    f32x4 acc[4][4];
#pragma unroll
    for (int i = 0; i < 4; i++)
#pragma unroll
        for (int j = 0; j < 4; j++) acc[i][j] = (f32x4){0.f, 0.f, 0.f, 0.f};

    size_t aBase[4], bBase[4];
#pragma unroll
    for (int f = 0; f < 4; f++) {
        aBase[f] = ((size_t)((m0 >> 4) + wr * 4 + f) * KB + kb0) * 512 + (size_t)lane * 8;
        bBase[f] = ((size_t)((n0 >> 4) + wc * 4 + f) * KB + kb0) * 512 + (size_t)lane * 8;
    }

#pragma unroll 2
    for (int kb = 0; kb < nkb; ++kb) {
        const size_t ko = (size_t)kb * 512;
        f16x8 a[4], b[4];
#pragma unroll
        for (int f = 0; f < 4; f++) {
            a[f] = *(const f16x8*)(A + aBase[f] + ko);
            b[f] = *(const f16x8*)(B + bBase[f] + ko);
        }
#pragma unroll
        for (int fm = 0; fm < 4; fm++)
#pragma unroll
            for (int fn = 0; fn < 4; fn++)
                acc[fm][fn] = __builtin_amdgcn_mfma_f32_16x16x32_f16(a[fm], b[fn], acc[fm][fn], 0, 0, 0);
    }

    float* po = part + (size_t)blockIdx.z * ((size_t)kMP * kNG);
#pragma unroll
    for (int fm = 0; fm < 4; fm++)
#pragma unroll
        for (int fn = 0; fn < 4; fn++) {
            const int row0 = m0 + wr * 64 + fm * 16 + ((lane >> 4) << 2);
            const int col  = n0 + wc * 64 + fn * 16 + (lane & 15);
#pragma unroll
            for (int j = 0; j < 4; j++)
                po[(size_t)(row0 + j) * kNG + col] = acc[fm][fn][j];
        }
}

// ---------------------------------------------------------------------------
// Reduce KSPLIT K-partials; mode 1: add velocity*W_ih^T, ReLU, store g (fp32)
// + packed-fp16 copies of h (always) and g (mode 1) for the next GEMMs.
// Grid: (4, kB), 256 threads, 4 g's per thread.
// ---------------------------------------------------------------------------
__global__ __launch_bounds__(256)
void k_reduce(const float* __restrict__ part,
              const float* __restrict__ velocity, const float* __restrict__ W_ih,
              float* __restrict__ gout, f16_t* __restrict__ gb,
              f16_t* __restrict__ hout, int t, int mode) {
    const int b = blockIdx.y;
    const int g = blockIdx.x * 1024 + threadIdx.x * 4;

    float4 s = *(const float4*)(part + (size_t)b * kNG + g);
    float v0 = s.x, v1 = s.y, v2 = s.z, v3 = s.w;
#pragma unroll
    for (int ks = 1; ks < KSPLIT; ks++) {
        float4 p = *(const float4*)(part + (size_t)ks * ((size_t)kMP * kNG) + (size_t)b * kNG + g);
        v0 += p.x; v1 += p.y; v2 += p.z; v3 += p.w;
    }
    if (mode == 1) {
        const float2 vel = *(const float2*)(velocity + ((size_t)t * kB + b) * 2);
        const float4 w01 = *(const float4*)(W_ih + (size_t)g * 2);
        const float4 w23 = *(const float4*)(W_ih + (size_t)g * 2 + 4);
        v0 = fmaxf(0.f, v0 + vel.x * w01.x + vel.y * w01.y);
        v1 = fmaxf(0.f, v1 + vel.x * w01.z + vel.y * w01.w);
        v2 = fmaxf(0.f, v2 + vel.x * w23.x + vel.y * w23.y);
        v3 = fmaxf(0.f, v3 + vel.x * w23.z + vel.y * w23.w);
        float4 o; o.x = v0; o.y = v1; o.z = v2; o.w = v3;
        *(float4*)(gout + ((size_t)t * kB + b) * kNG + g) = o;
    }
    f16x4 h4;
    h4[0] = (f16_t)v0; h4[1] = (f16_t)v1; h4[2] = (f16_t)v2; h4[3] = (f16_t)v3;

    // packed-fragment positions: kb = g>>5, lane = ((g>>3)&3)*16 + (row&15),
    // within-lane elem offset = g&7 (thread's 4 g's stay in one 8-elem slot).
    const int kbg = g >> 5;
    {
        const int laneh = ((g >> 3) & 3) * 16 + (b & 15);
        const size_t off = ((size_t)((b >> 4) * 128 + kbg) * 64 + laneh) * 8 + (g & 7);
        *(f16x4*)(hout + off) = h4;
    }
    if (mode == 1 && gb) {
        const int r = t * kB + b;
        const int laneg = ((g >> 3) & 3) * 16 + (r & 15);
        const size_t off = ((size_t)((r >> 4) * 128 + kbg) * 64 + laneg) * 8 + (g & 7);
        *(f16x4*)(gb + off) = h4;
    }
}

// ---------------------------------------------------------------------------
// Decoder: logits[r][p] = sum_g G[r][g] * Wdec[p][g] on packed operands.
// LDS-free like k_gemm_pk.  Flat grid 632, XCD-colocated decode (4 n-tiles
// of an m-panel on one XCD so G rows hit that L2 once).
// ---------------------------------------------------------------------------
__global__ __launch_bounds__(256)
void k_dec_pk(const f16_t* __restrict__ G, const f16_t* __restrict__ Wd,
              float* __restrict__ out) {
    const int bid  = blockIdx.x;        // 0..631
    const int xcd  = bid & 7;
    const int idx  = bid >> 3;          // 0..78
    const int tile = xcd * 79 + idx;    // tile = m_t*4 + n_t
    if (tile >= 157 * 4) return;
    const int m0 = (tile >> 2) * 128;
    const int n0 = (tile & 3) * 128;

    const int tid  = threadIdx.x;
    const int lane = tid & 63;
    const int wid  = tid >> 6;
    const int wr   = wid >> 1;
    const int wc   = wid & 1;
    const int M    = kSEQ * kB;   // 20000
    const int KB   = kNG / 32;    // 128

    f32x4 acc[4][4];
#pragma unroll
    for (int i = 0; i < 4; i++)
#pragma unroll
        for (int j = 0; j < 4; j++) acc[i][j] = (f32x4){0.f, 0.f, 0.f, 0.f};

    size_t aBase[4], bBase[4];
#pragma unroll
    for (int f = 0; f < 4; f++) {
        aBase[f] = (size_t)((m0 >> 4) + wr * 4 + f) * KB * 512 + (size_t)lane * 8;
        bBase[f] = (size_t)((n0 >> 4) + wc * 4 + f) * KB * 512 + (size_t)lane * 8;
    }

#pragma unroll 2
    for (int kb = 0; kb < KB; ++kb) {
        const size_t ko = (size_t)kb * 512;
        f16x8 a[4], b[4];
#pragma unroll
        for (int f = 0; f < 4; f++) {
            a[f] = *(const f16x8*)(G + aBase[f] + ko);
            b[f] = *(const f16x8*)(Wd + bBase[f] + ko);
        }
#pragma unroll
        for (int fm = 0; fm < 4; fm++)
#pragma unroll
            for (int fn = 0; fn < 4; fn++)
                acc[fm][fn] = __builtin_amdgcn_mfma_f32_16x16x32_f16(a[fm], b[fn], acc[fm][fn], 0, 0, 0);
    }

#pragma unroll
    for (int fm = 0; fm < 4; fm++)
#pragma unroll
        for (int fn = 0; fn < 4; fn++) {
            const int row0 = m0 + wr * 64 + fm * 16 + ((lane >> 4) << 2);
            const int col  = n0 + wc * 64 + fn * 16 + (lane & 15);
#pragma unroll
            for (int j = 0; j < 4; j++) {
                const int row = row0 + j;
                if (row < M) out[(size_t)row * kNP + col] = acc[fm][fn][j];
            }
        }
}

// ---------------------------------------------------------------------------
extern "C" void kernel_launch(void* const* d_in, const int* in_sizes, int n_in,
                              void* d_out, int out_size, void* d_ws, size_t ws_size,
                              hipStream_t stream) {
    const float* velocity = (const float*)d_in[0];
    const float* init_pc  = (const float*)d_in[1];
    const float* W_enc    = (const float*)d_in[2];
    const float* W_ih     = (const float*)d_in[3];
    const float* W_hh     = (const float*)d_in[4];
    const float* W_dec    = (const float*)d_in[5];

    float* logits = (float*)d_out;                         // (100,200,512)
    float* gout   = logits + (size_t)kSEQ * kB * kNP;      // (100,200,4096)

    char* ws = (char*)d_ws;
    size_t off = 0;
    auto alloc = [&](size_t bytes) -> void* {
        void* p = ws + off;
        off += (bytes + 255) & ~(size_t)255;
        return p;
    };
    // fragment-packed buffers ([M/16][K/32] fragments of 512 f16 each)
    f16_t* whh_pk  = (f16_t*)alloc((size_t)256 * 128 * 512 * 2);   // 33.5 MB
    f16_t* wenc_pk = (f16_t*)alloc((size_t)256 * 16 * 512 * 2);    //  4.2 MB
    f16_t* wdec_pk = (f16_t*)alloc((size_t)32 * 128 * 512 * 2);    //  4.2 MB
    f16_t* ip_pk   = (f16_t*)alloc((size_t)16 * 16 * 512 * 2);     //  0.26 MB
    f16_t* h_pk[2];
    h_pk[0] = (f16_t*)alloc((size_t)16 * 128 * 512 * 2);           //  2.1 MB
    h_pk[1] = (f16_t*)alloc((size_t)16 * 128 * 512 * 2);
    float* partial = (float*)alloc((size_t)KSPLIT * kMP * kNG * 4);// 33.5 MB
    // packed fp16 copy of g for the decoder (20096 rows -> 1256 m16 groups)
    f16_t* gb_pk = nullptr;
    if (ws_size >= off + (size_t)1256 * 128 * 512 * 2 + 4096)
        gb_pk = (f16_t*)alloc((size_t)1256 * 128 * 512 * 2);       // 164.6 MB

    // --- pack weights / initial state into fragment order ---
    int nf;
    nf = 256 * 128;  // W_hh (4096 x 4096)
    k_pack<<<(nf + 3) / 4, 256, 0, stream>>>(W_hh, whh_pk, 128, kNG, kNG, nf);
    nf = 256 * 16;   // W_enc (4096 x 512)
    k_pack<<<(nf + 3) / 4, 256, 0, stream>>>(W_enc, wenc_pk, 16, kNG, kNP, nf);
    nf = 32 * 128;   // W_dec (512 x 4096)
    k_pack<<<(nf + 3) / 4, 256, 0, stream>>>(W_dec, wdec_pk, 128, kNP, kNG, nf);
    nf = 16 * 16;    // init_pc (200 x 512, zero-padded to 256 rows)
    k_pack<<<(nf + 3) / 4, 256, 0, stream>>>(init_pc, ip_pk, 16, kB, kNP, nf);

    dim3 gG(kNG / 128, kMP / 128, KSPLIT);   // (32, 2, 8) = 512 blocks
    dim3 gR(4, kB);

    // --- encoder: h0 = init_pc @ W_enc^T ---
    k_gemm_pk<<<gG, 256, 0, stream>>>(ip_pk, wenc_pk, kNP / 32, partial);
    k_reduce<<<gR, 256, 0, stream>>>(partial, velocity, W_ih, nullptr, nullptr, h_pk[0], 0, 0);

    // --- recurrent scan ---
    int p = 0;
    for (int t = 0; t < kSEQ; t++) {
        k_gemm_pk<<<gG, 256, 0, stream>>>(h_pk[p], whh_pk, kNG / 32, partial);
        k_reduce<<<gR, 256, 0, stream>>>(partial, velocity, W_ih, gout, gb_pk, h_pk[p ^ 1], t, 1);
        p ^= 1;
    }

    // --- decoder ---
    k_dec_pk<<<632, 256, 0, stream>>>(gb_pk, wdec_pk, logits);
}